// Round 5
// baseline (537.307 us; speedup 1.0000x reference)
//
#include <hip/hip_runtime.h>
#include <hip/hip_bf16.h>
#include <stdint.h>

#define L_DIM 1024
#define B_DIM 32
#define D_DIM 1024
#define M_DIM (L_DIM * B_DIM)        // 32768 GEMM rows
#define N3_DIM (3 * D_DIM)           // 3072 GEMM cols (u0 | f | r regions)
#define K_DIM D_DIM                  // 1024
#define LBD ((int64_t)L_DIM * B_DIM * D_DIM)  // 33554432
#define NBD (B_DIM * D_DIM)          // 32768 chains
#define NCHUNK 32
#define CLEN 32

// GEMM tiling
#define BM 256
#define BN 256
#define BK 64
#define NMT (M_DIM / BM)   // 128
#define NNT (N3_DIM / BN)  // 12
#define NKT (K_DIM / BK)   // 16
#define NITER (NKT / 2)    // 8

typedef __bf16 bf16_t;
typedef bf16_t bf16x8 __attribute__((ext_vector_type(8)));
typedef float f32x4 __attribute__((ext_vector_type(4)));
typedef float f32x16 __attribute__((ext_vector_type(16)));

// RTNE fp32 -> bf16 bits
__device__ __forceinline__ unsigned short f2bf(float f) {
    union { float f; unsigned u; } v; v.f = f;
    unsigned u = v.u;
    u += 0x7FFFu + ((u >> 16) & 1u);
    return (unsigned short)(u >> 16);
}
__device__ __forceinline__ float bf2f(unsigned short h) {
    union { unsigned u; float f; } v; v.u = ((unsigned)h) << 16;
    return v.f;
}

// ---------------- convert x: fp32 [L,B,D] -> bf16 [M,K] ----------------
__global__ void cvt_x_kernel(const float* __restrict__ x, unsigned short* __restrict__ xb) {
    int64_t i0 = ((int64_t)blockIdx.x * blockDim.x + threadIdx.x) * 4;
    int64_t stride = (int64_t)gridDim.x * blockDim.x * 4;
    for (int64_t i = i0; i < LBD; i += stride) {
        float4 v = *reinterpret_cast<const float4*>(x + i);
        ushort4 o;
        o.x = f2bf(v.x); o.y = f2bf(v.y); o.z = f2bf(v.z); o.w = f2bf(v.w);
        *reinterpret_cast<ushort4*>(xb + i) = o;
    }
}

// ------------- convert weight: [i(1024)][o(1024)][k(3)] fp32 -> wT [n=k*1024+o][i] bf16 -------------
__global__ void cvt_w_kernel(const float* __restrict__ w, unsigned short* __restrict__ wT) {
    __shared__ float tile[64][65];
    int bid = blockIdx.x;               // 768 = 3(k) * 16(o-tiles) * 16(i-tiles)
    int k  = bid >> 8;
    int o0 = ((bid >> 4) & 15) * 64;
    int i0 = (bid & 15) * 64;
    int t = threadIdx.x;
    {
        int o = t & 63, ib = t >> 6;
        #pragma unroll
        for (int it = 0; it < 16; ++it) {
            int i = ib + it * 4;
            tile[o][i] = w[((int64_t)(i0 + i) * 1024 + (o0 + o)) * 3 + k];
        }
    }
    __syncthreads();
    {
        int i = t & 63, ob = t >> 6;
        #pragma unroll
        for (int ot = 0; ot < 16; ++ot) {
            int o = ob + ot * 4;
            wT[(int64_t)(k * 1024 + o0 + o) * 1024 + (i0 + i)] = f2bf(tile[o][i]);
        }
    }
}

// ---------------- GEMM: 256x256 tile, 8 waves, 8-phase dbuf schedule, 32x32x16 MFMA ----------------
__device__ __forceinline__ void gload_lds16(const void* g, void* l) {
    __builtin_amdgcn_global_load_lds(
        (const __attribute__((address_space(1))) unsigned int*)g,
        (__attribute__((address_space(3))) unsigned int*)l,
        16, 0, 0);
}

#define BARRIER() do { asm volatile("" ::: "memory"); __builtin_amdgcn_s_barrier(); asm volatile("" ::: "memory"); } while (0)
#define WAIT_LGKM0() asm volatile("s_waitcnt lgkmcnt(0)" ::: "memory")
#define WAIT_LGKM8() asm volatile("s_waitcnt lgkmcnt(8)" ::: "memory")
#define VMCNT(n) asm volatile("s_waitcnt vmcnt(" #n ")" ::: "memory")

__global__ __launch_bounds__(512, 2) void gemm_kernel(
    const unsigned short* __restrict__ A,    // [32768][1024] bf16 bits
    const unsigned short* __restrict__ Bt,   // [3072][1024] bf16 bits
    const float* __restrict__ bias,          // [2048]
    float* __restrict__ u0_out,              // d_out + LBD: u0 fp32
    unsigned short* __restrict__ fb,         // ws: f bf16
    unsigned short* __restrict__ rb)         // ws: r bf16
{
    // 128 KiB: [buf][half][128 rows][64 cols] for A (M-halves) and B (N-halves)
    __shared__ __align__(16) unsigned short a_lds[2][2][128 * 64];
    __shared__ __align__(16) unsigned short b_lds[2][2][128 * 64];

    int bid = blockIdx.x;
    int swz = (bid & 7) * (NMT * NNT / 8) + (bid >> 3);   // 1536 % 8 == 0 -> bijective
    int nt = swz % NNT, mt = swz / NNT;
    int m0 = mt * BM, n0 = nt * BN;

    int tid = threadIdx.x;
    int w = tid >> 6, lane = tid & 63;
    int wm = w >> 2, wn = w & 3;           // 2(M) x 4(N) wave grid; per-wave out 128x64
    int l31 = lane & 31, l5 = lane >> 5;
    int lane7 = lane & 7;                  // row&7 for read-side XOR (row low bits = lane&7)

    // staging: 2 x gload_lds16 per half-tile per thread; source col pre-swizzled
    int srow = w * 8 + (lane >> 3);
    int scol = ((lane & 7) ^ ((lane >> 3) & 7)) << 3;
    const unsigned short* Asrc = A  + (int64_t)(m0 + srow) * K_DIM + scol;
    const unsigned short* Bsrc = Bt + (int64_t)(n0 + srow) * K_DIM + scol;
    unsigned short* dstA = &a_lds[0][0][0] + w * 8 * 64;   // lane adds 16B linearly
    unsigned short* dstB = &b_lds[0][0][0] + w * 8 * 64;

    auto stageA = [&](int buf, int half, int kt) {
        if (kt >= NKT) return;
        const unsigned short* s = Asrc + (int64_t)half * 128 * K_DIM + kt * BK;
        unsigned short* d = dstA + (buf * 2 + half) * (128 * 64);
        gload_lds16(s, d);
        gload_lds16(s + (int64_t)64 * K_DIM, d + 64 * 64);
    };
    auto stageB = [&](int buf, int half, int kt) {
        if (kt >= NKT) return;
        const unsigned short* s = Bsrc + (int64_t)half * 128 * K_DIM + kt * BK;
        unsigned short* d = dstB + (buf * 2 + half) * (128 * 64);
        gload_lds16(s, d);
        gload_lds16(s + (int64_t)64 * K_DIM, d + 64 * 64);
    };

    // A-frag for 32x32x16: row = rf*32 + (lane&31); k-chunk = ks*2 + (lane>>5), XOR row&7
    auto rdA_ = [&](int buf, int mh, int rf2, int ks) -> bf16x8 {
        int rr = wm * 64 + rf2 * 32 + l31;
        int pc = ((ks * 2 + l5) ^ lane7) << 3;
        return *reinterpret_cast<const bf16x8*>(&a_lds[buf][mh][rr * 64 + pc]);
    };
    auto rdB_ = [&](int buf, int nh, int ks) -> bf16x8 {
        int rr = wn * 32 + l31;
        int pc = ((ks * 2 + l5) ^ lane7) << 3;
        return *reinterpret_cast<const bf16x8*>(&b_lds[buf][nh][rr * 64 + pc]);
    };

    f32x16 acc[4][2];   // [mh*2+rf2][nh]
    #pragma unroll
    for (int i = 0; i < 4; ++i)
        #pragma unroll
        for (int j = 0; j < 2; ++j)
            #pragma unroll
            for (int e = 0; e < 16; ++e) acc[i][j][e] = 0.f;

    bf16x8 af[2][4], b0[4], b1[4];

#define QUAD(MH, NH, BB)                                                            \
    do {                                                                            \
        __builtin_amdgcn_s_setprio(1);                                              \
        _Pragma("unroll")                                                           \
        for (int rf2 = 0; rf2 < 2; ++rf2)                                           \
            _Pragma("unroll")                                                       \
            for (int ks = 0; ks < 4; ++ks)                                          \
                acc[(MH)*2 + rf2][(NH)] =                                           \
                    __builtin_amdgcn_mfma_f32_32x32x16_bf16(                        \
                        af[rf2][ks], BB[ks], acc[(MH)*2 + rf2][(NH)], 0, 0, 0);     \
        __builtin_amdgcn_s_setprio(0);                                              \
    } while (0)

    // prologue: tile0 fully (buf0: A0,B0,B1,A1) + tile1 partial (buf1: A0,B0,B1)
    stageA(0, 0, 0);
    stageB(0, 0, 0);
    stageB(0, 1, 0);
    stageA(0, 1, 0);
    stageA(1, 0, 1);
    stageB(1, 0, 1);
    stageB(1, 1, 1);
    VMCNT(6);          // tile0's 8 loads landed; tile1's 6 may be in flight
    BARRIER();

    for (int t = 0; t < NITER; ++t) {
        int t2 = t * 2;
        // ---- P1: read buf0 A0(8)+B0(4), stage buf1.A1 <- t2+1, MFMA (0,0)
        #pragma unroll
        for (int rf2 = 0; rf2 < 2; ++rf2)
            #pragma unroll
            for (int ks = 0; ks < 4; ++ks) af[rf2][ks] = rdA_(0, 0, rf2, ks);
        #pragma unroll
        for (int ks = 0; ks < 4; ++ks) b0[ks] = rdB_(0, 0, ks);
        stageA(1, 1, t2 + 1);
        WAIT_LGKM8();
        BARRIER();
        WAIT_LGKM0();
        QUAD(0, 0, b0);
        BARRIER();
        // ---- P2: read buf0 B1 (4), stage buf0.A0 <- t2+2, MFMA (0,1)
        #pragma unroll
        for (int ks = 0; ks < 4; ++ks) b1[ks] = rdB_(0, 1, ks);
        stageA(0, 0, t2 + 2);
        BARRIER();
        WAIT_LGKM0();
        QUAD(0, 1, b1);
        BARRIER();
        // ---- P3: read buf0 A1 (8), stage buf0.B0 <- t2+2, MFMA (1,0)
        #pragma unroll
        for (int rf2 = 0; rf2 < 2; ++rf2)
            #pragma unroll
            for (int ks = 0; ks < 4; ++ks) af[rf2][ks] = rdA_(0, 1, rf2, ks);
        stageB(0, 0, t2 + 2);
        BARRIER();
        WAIT_LGKM0();
        QUAD(1, 0, b0);
        BARRIER();
        // ---- P4: stage buf0.B1 <- t2+2, vmcnt, MFMA (1,1)
        stageB(0, 1, t2 + 2);
        if (t < NITER - 1) { VMCNT(6); } else { VMCNT(0); }
        BARRIER();
        QUAD(1, 1, b1);
        BARRIER();
        // ---- P5: read buf1 A0(8)+B0(4), stage buf0.A1 <- t2+2, MFMA (0,0)
        #pragma unroll
        for (int rf2 = 0; rf2 < 2; ++rf2)
            #pragma unroll
            for (int ks = 0; ks < 4; ++ks) af[rf2][ks] = rdA_(1, 0, rf2, ks);
        #pragma unroll
        for (int ks = 0; ks < 4; ++ks) b0[ks] = rdB_(1, 0, ks);
        stageA(0, 1, t2 + 2);
        WAIT_LGKM8();
        BARRIER();
        WAIT_LGKM0();
        QUAD(0, 0, b0);
        BARRIER();
        // ---- P6: read buf1 B1 (4), stage buf1.A0 <- t2+3, MFMA (0,1)
        #pragma unroll
        for (int ks = 0; ks < 4; ++ks) b1[ks] = rdB_(1, 1, ks);
        stageA(1, 0, t2 + 3);
        BARRIER();
        WAIT_LGKM0();
        QUAD(0, 1, b1);
        BARRIER();
        // ---- P7: read buf1 A1 (8), stage buf1.B0 <- t2+3, MFMA (1,0)
        #pragma unroll
        for (int rf2 = 0; rf2 < 2; ++rf2)
            #pragma unroll
            for (int ks = 0; ks < 4; ++ks) af[rf2][ks] = rdA_(1, 1, rf2, ks);
        stageB(1, 0, t2 + 3);
        BARRIER();
        WAIT_LGKM0();
        QUAD(1, 0, b0);
        BARRIER();
        // ---- P8: stage buf1.B1 <- t2+3, vmcnt, MFMA (1,1)
        stageB(1, 1, t2 + 3);
        if (t < NITER - 1) { VMCNT(6); } else { VMCNT(0); }
        BARRIER();
        QUAD(1, 1, b1);
        BARRIER();
    }

    // epilogue: 32x32 C layout: col=lane&31, row=(reg&3)+8*(reg>>2)+4*(lane>>5)
    int region = n0 >> 10;
    #pragma unroll
    for (int i = 0; i < 4; ++i) {
        int mh = i >> 1, rf2 = i & 1;
        #pragma unroll
        for (int j = 0; j < 2; ++j) {
            f32x16 v = acc[i][j];
            int rbase = m0 + mh * 128 + wm * 64 + rf2 * 32 + (l5 << 2);
            int col = (n0 + j * 128 + wn * 32 + l31) & 1023;
            #pragma unroll
            for (int reg = 0; reg < 16; ++reg) {
                int row = rbase + (reg & 3) + ((reg >> 2) << 3);
                int64_t idx = (int64_t)row * 1024 + col;
                float val = v[reg];
                if (region == 0) {
                    u0_out[idx] = val;
                } else if (region == 1) {
                    fb[idx] = f2bf(1.0f / (1.0f + __expf(-(val + bias[col]))));
                } else {
                    rb[idx] = f2bf(1.0f / (1.0f + __expf(-(val + bias[1024 + col]))));
                }
            }
        }
    }
#undef QUAD
}

// ---------------- chunked parallel scan ----------------
// c_t = f_t*c_{t-1} + (1-f_t)*u0_t. Chunk transfer: c_out = A*c_in + B.

__global__ void scan_phase1(const unsigned short* __restrict__ fb,
                            const float* __restrict__ u0_arr,
                            float* __restrict__ Aout, float* __restrict__ Bout) {
    int t = blockIdx.x * blockDim.x + threadIdx.x;   // chunk*NBD + idx
    int idx = t & (NBD - 1);
    int chunk = t >> 15;
    int64_t base = (int64_t)chunk * CLEN * NBD + idx;
    float Ap = 1.0f, Bv = 0.0f;
    #pragma unroll 8
    for (int i = 0; i < CLEN; ++i, base += NBD) {
        float f = bf2f(fb[base]);
        float u0 = u0_arr[base];
        Bv = u0 + f * (Bv - u0);
        Ap *= f;
    }
    Aout[t] = Ap; Bout[t] = Bv;
}

__global__ void scan_phase2(const float* __restrict__ c0, const float* __restrict__ Aarr,
                            const float* __restrict__ Barr, float* __restrict__ cin) {
    int idx = blockIdx.x * blockDim.x + threadIdx.x; // 0..NBD-1
    float c = c0[idx];
    #pragma unroll
    for (int ch = 0; ch < NCHUNK; ++ch) {
        cin[ch * NBD + idx] = c;
        c = Aarr[ch * NBD + idx] * c + Barr[ch * NBD + idx];
    }
}

__global__ void scan_phase3(const float* __restrict__ x,
                            const unsigned short* __restrict__ fb,
                            const unsigned short* __restrict__ rb,
                            const float* __restrict__ cin,
                            float* __restrict__ out_h, float* __restrict__ out_c) {
    int t = blockIdx.x * blockDim.x + threadIdx.x;
    int idx = t & (NBD - 1);
    int chunk = t >> 15;
    float c = cin[t];
    int64_t base = (int64_t)chunk * CLEN * NBD + idx;
    #pragma unroll 4
    for (int i = 0; i < CLEN; ++i, base += NBD) {
        float f  = bf2f(fb[base]);
        float u0 = out_c[base];     // u0 written by gemm epilogue
        c = u0 + f * (c - u0);      // f*c + (1-f)*u0
        out_c[base] = c;
        float e = __expf(2.0f * c); // tanh via exp; |c| bounded so no overflow
        float g = (e - 1.0f) / (e + 1.0f);
        float r = bf2f(rb[base]);
        float xv = x[base];
        out_h[base] = xv + r * (g - xv);
    }
}

extern "C" void kernel_launch(void* const* d_in, const int* in_sizes, int n_in,
                              void* d_out, int out_size, void* d_ws, size_t ws_size,
                              hipStream_t stream) {
    const float* x    = (const float*)d_in[0];
    const float* c0   = (const float*)d_in[1];
    const float* wgt  = (const float*)d_in[2];
    const float* bias = (const float*)d_in[3];
    float* out = (float*)d_out;

    unsigned short* xb = (unsigned short*)d_ws;                 // 64 MB (dead after gemm)
    unsigned short* wT = xb + (int64_t)M_DIM * K_DIM;           // +6 MB
    unsigned short* fb = wT + (int64_t)N3_DIM * K_DIM;          // +64 MB, f bf16
    unsigned short* rb = fb + LBD;                              // +64 MB, r bf16

    // A/B/cin overlay the xb region (xb is dead once gemm completes)
    float* Aarr = (float*)d_ws;                                 // 4 MB
    float* Barr = Aarr + NCHUNK * NBD;                          // 4 MB
    float* cin  = Barr + NCHUNK * NBD;                          // 4 MB

    cvt_x_kernel<<<8192, 256, 0, stream>>>(x, xb);
    cvt_w_kernel<<<768, 256, 0, stream>>>(wgt, wT);
    gemm_kernel<<<NMT * NNT, 512, 0, stream>>>(xb, wT, bias, out + LBD, fb, rb);
    scan_phase1<<<(NCHUNK * NBD) / 256, 256, 0, stream>>>(fb, out + LBD, Aarr, Barr);
    scan_phase2<<<NBD / 256, 256, 0, stream>>>(c0, Aarr, Barr, cin);
    scan_phase3<<<(NCHUNK * NBD) / 256, 256, 0, stream>>>(x, fb, rb, cin, out, out + LBD);
}

// Round 6
// 506.636 us; speedup vs baseline: 1.0605x; 1.0605x over previous
//
#include <hip/hip_runtime.h>
#include <hip/hip_bf16.h>
#include <stdint.h>

#define L_DIM 1024
#define B_DIM 32
#define D_DIM 1024
#define M_DIM (L_DIM * B_DIM)        // 32768 GEMM rows
#define N3_DIM (3 * D_DIM)           // 3072 GEMM cols (u0 | f | r regions)
#define K_DIM D_DIM                  // 1024
#define LBD ((int64_t)L_DIM * B_DIM * D_DIM)  // 33554432
#define NBD (B_DIM * D_DIM)          // 32768 chains
#define NCHUNK 32
#define CLEN 32

// GEMM tiling
#define BM 256
#define BN 256
#define BK 64
#define NMT (M_DIM / BM)   // 128
#define NNT (N3_DIM / BN)  // 12
#define NKT (K_DIM / BK)   // 16
#define NITER (NKT / 2)    // 8

typedef __bf16 bf16_t;
typedef bf16_t bf16x8 __attribute__((ext_vector_type(8)));
typedef float f32x4 __attribute__((ext_vector_type(4)));

// RTNE fp32 -> bf16 bits
__device__ __forceinline__ unsigned short f2bf(float f) {
    union { float f; unsigned u; } v; v.f = f;
    unsigned u = v.u;
    u += 0x7FFFu + ((u >> 16) & 1u);
    return (unsigned short)(u >> 16);
}
__device__ __forceinline__ float bf2f(unsigned short h) {
    union { unsigned u; float f; } v; v.u = ((unsigned)h) << 16;
    return v.f;
}

// ---------------- convert x: fp32 [L,B,D] -> bf16 [M,K] ----------------
__global__ void cvt_x_kernel(const float* __restrict__ x, unsigned short* __restrict__ xb) {
    int64_t i0 = ((int64_t)blockIdx.x * blockDim.x + threadIdx.x) * 4;
    int64_t stride = (int64_t)gridDim.x * blockDim.x * 4;
    for (int64_t i = i0; i < LBD; i += stride) {
        float4 v = *reinterpret_cast<const float4*>(x + i);
        ushort4 o;
        o.x = f2bf(v.x); o.y = f2bf(v.y); o.z = f2bf(v.z); o.w = f2bf(v.w);
        *reinterpret_cast<ushort4*>(xb + i) = o;
    }
}

// ------------- convert weight: [i(1024)][o(1024)][k(3)] fp32 -> wT [n=k*1024+o][i] bf16 -------------
__global__ void cvt_w_kernel(const float* __restrict__ w, unsigned short* __restrict__ wT) {
    __shared__ float tile[64][65];
    int bid = blockIdx.x;               // 768 = 3(k) * 16(o-tiles) * 16(i-tiles)
    int k  = bid >> 8;
    int o0 = ((bid >> 4) & 15) * 64;
    int i0 = (bid & 15) * 64;
    int t = threadIdx.x;
    {
        int o = t & 63, ib = t >> 6;
        #pragma unroll
        for (int it = 0; it < 16; ++it) {
            int i = ib + it * 4;
            tile[o][i] = w[((int64_t)(i0 + i) * 1024 + (o0 + o)) * 3 + k];
        }
    }
    __syncthreads();
    {
        int i = t & 63, ob = t >> 6;
        #pragma unroll
        for (int ot = 0; ot < 16; ++ot) {
            int o = ob + ot * 4;
            wT[(int64_t)(k * 1024 + o0 + o) * 1024 + (i0 + i)] = f2bf(tile[o][i]);
        }
    }
}

// ---------------- GEMM: 256x256, 8 waves, 8-phase dbuf, read-ahead pipeline, 1 barrier/phase ----------------
__device__ __forceinline__ void gload_lds16(const void* g, void* l) {
    __builtin_amdgcn_global_load_lds(
        (const __attribute__((address_space(1))) unsigned int*)g,
        (__attribute__((address_space(3))) unsigned int*)l,
        16, 0, 0);
}

#define BARRIER() do { asm volatile("" ::: "memory"); __builtin_amdgcn_s_barrier(); asm volatile("" ::: "memory"); } while (0)
#define WAIT_LGKM0() asm volatile("s_waitcnt lgkmcnt(0)" ::: "memory")
#define VMCNT(n) asm volatile("s_waitcnt vmcnt(" #n ")" ::: "memory")

__global__ __launch_bounds__(512, 2) void gemm_kernel(
    const unsigned short* __restrict__ A,    // [32768][1024] bf16 bits
    const unsigned short* __restrict__ Bt,   // [3072][1024] bf16 bits
    const float* __restrict__ bias,          // [2048]
    float* __restrict__ u0_out,              // d_out + LBD: u0 fp32
    unsigned short* __restrict__ fb,         // ws: f bf16
    unsigned short* __restrict__ rb)         // ws: r bf16
{
    // 128 KiB: [buf][half][128 rows][64 cols] for A (M-halves) and B (N-halves)
    __shared__ __align__(16) unsigned short a_lds[2][2][128 * 64];
    __shared__ __align__(16) unsigned short b_lds[2][2][128 * 64];

    int bid = blockIdx.x;
    int swz = (bid & 7) * (NMT * NNT / 8) + (bid >> 3);   // 1536 % 8 == 0 -> bijective
    int nt = swz % NNT, mt = swz / NNT;
    int m0 = mt * BM, n0 = nt * BN;

    int tid = threadIdx.x;
    int w = tid >> 6, lane = tid & 63;
    int wm = w >> 2, wn = w & 3;           // 2(M) x 4(N) wave grid
    int l15 = lane & 15, l4 = lane >> 4;
    int pcx = l15 & 7;                     // row&7 for read-side XOR swizzle

    // staging: 2 x gload_lds16 per half-tile per thread; source col pre-swizzled
    int srow = w * 8 + (lane >> 3);
    int scol = ((lane & 7) ^ ((lane >> 3) & 7)) << 3;
    const unsigned short* Asrc = A  + (int64_t)(m0 + srow) * K_DIM + scol;
    const unsigned short* Bsrc = Bt + (int64_t)(n0 + srow) * K_DIM + scol;
    unsigned short* dstA = &a_lds[0][0][0] + w * 8 * 64;   // lane adds 16B linearly
    unsigned short* dstB = &b_lds[0][0][0] + w * 8 * 64;

    auto stageA = [&](int buf, int half, int kt) {
        if (kt >= NKT) return;
        const unsigned short* s = Asrc + (int64_t)half * 128 * K_DIM + kt * BK;
        unsigned short* d = dstA + (buf * 2 + half) * (128 * 64);
        gload_lds16(s, d);
        gload_lds16(s + (int64_t)64 * K_DIM, d + 64 * 64);
    };
    auto stageB = [&](int buf, int half, int kt) {
        if (kt >= NKT) return;
        const unsigned short* s = Bsrc + (int64_t)half * 128 * K_DIM + kt * BK;
        unsigned short* d = dstB + (buf * 2 + half) * (128 * 64);
        gload_lds16(s, d);
        gload_lds16(s + (int64_t)64 * K_DIM, d + 64 * 64);
    };

    auto rdA_ = [&](int buf, int mh, int im, int ks) -> bf16x8 {
        int rr = wm * 64 + im * 16 + l15;
        int pc = ((ks * 4 + l4) ^ pcx) << 3;
        return *reinterpret_cast<const bf16x8*>(&a_lds[buf][mh][rr * 64 + pc]);
    };
    auto rdB_ = [&](int buf, int nh, int jn, int ks) -> bf16x8 {
        int rr = wn * 32 + jn * 16 + l15;
        int pc = ((ks * 4 + l4) ^ pcx) << 3;
        return *reinterpret_cast<const bf16x8*>(&b_lds[buf][nh][rr * 64 + pc]);
    };

    f32x4 acc[8][4];
    #pragma unroll
    for (int i = 0; i < 8; ++i)
        #pragma unroll
        for (int j = 0; j < 4; ++j) acc[i][j] = (f32x4){0.f, 0.f, 0.f, 0.f};

    bf16x8 af[4][2], b0[2][2], b1[2][2];

#define RD_A(BUF, MH)                                                               \
    do {                                                                            \
        _Pragma("unroll")                                                           \
        for (int im = 0; im < 4; ++im) {                                            \
            af[im][0] = rdA_((BUF), (MH), im, 0);                                   \
            af[im][1] = rdA_((BUF), (MH), im, 1);                                   \
        }                                                                           \
    } while (0)
#define RD_B(DST, BUF, NH)                                                          \
    do {                                                                            \
        _Pragma("unroll")                                                           \
        for (int jn = 0; jn < 2; ++jn) {                                            \
            DST[jn][0] = rdB_((BUF), (NH), jn, 0);                                  \
            DST[jn][1] = rdB_((BUF), (NH), jn, 1);                                  \
        }                                                                           \
    } while (0)
#define QUAD(MH, NH, BB)                                                            \
    do {                                                                            \
        __builtin_amdgcn_s_setprio(1);                                              \
        _Pragma("unroll")                                                           \
        for (int im = 0; im < 4; ++im)                                              \
            _Pragma("unroll")                                                       \
            for (int jn = 0; jn < 2; ++jn)                                          \
                _Pragma("unroll")                                                   \
                for (int ks = 0; ks < 2; ++ks)                                      \
                    acc[(MH)*4 + im][(NH)*2 + jn] =                                 \
                        __builtin_amdgcn_mfma_f32_16x16x32_bf16(                    \
                            af[im][ks], BB[jn][ks], acc[(MH)*4 + im][(NH)*2 + jn],  \
                            0, 0, 0);                                               \
        __builtin_amdgcn_s_setprio(0);                                              \
    } while (0)

    // prologue: tile0 fully (buf0: A0,B0,B1,A1) + tile1 partial (buf1: A0,B0,B1)
    stageA(0, 0, 0);
    stageB(0, 0, 0);
    stageB(0, 1, 0);
    stageA(0, 1, 0);
    stageA(1, 0, 1);
    stageB(1, 0, 1);
    stageB(1, 1, 1);
    VMCNT(2);          // all but buf1.B1 landed (incl. buf0.A0/B0/B1/A1, buf1.A0/B0)
    BARRIER();
    RD_A(0, 0);        // af <- buf0.A0
    RD_B(b0, 0, 0);    // b0 <- buf0.B0

    #pragma unroll 1
    for (int t = 0; t < NITER; ++t) {
        int t2 = t * 2;
        // ---- P1: Q(0,0) on buf0; pre-read b1<-buf0.B1; stage buf1.A1<-t2+1
        BARRIER();
        WAIT_LGKM0();
        RD_B(b1, 0, 1);
        QUAD(0, 0, b0);
        stageA(1, 1, t2 + 1);
        // ---- P2: Q(0,1); post-read af<-buf0.A1; stage buf0.A0<-t2+2
        BARRIER();
        WAIT_LGKM0();
        QUAD(0, 1, b1);
        RD_A(0, 1);
        stageA(0, 0, t2 + 2);
        // ---- P3: Q(1,0); post-read b0<-buf1.B0; stage buf0.B0<-t2+2
        BARRIER();
        WAIT_LGKM0();
        QUAD(1, 0, b0);
        RD_B(b0, 1, 0);
        stageB(0, 0, t2 + 2);
        // ---- P4: Q(1,1); post-read af<-buf1.A0; stage buf0.B1<-t2+2; vmcnt
        BARRIER();
        QUAD(1, 1, b1);
        RD_A(1, 0);
        stageB(0, 1, t2 + 2);
        if (t < NITER - 1) { VMCNT(2); } else { VMCNT(0); }
        // ---- P5: Q(0,0) on buf1; pre-read b1<-buf1.B1; stage buf0.A1<-t2+2
        BARRIER();
        WAIT_LGKM0();
        RD_B(b1, 1, 1);
        QUAD(0, 0, b0);
        stageA(0, 1, t2 + 2);
        // ---- P6: Q(0,1); post-read af<-buf1.A1; stage buf1.A0<-t2+3
        BARRIER();
        WAIT_LGKM0();
        QUAD(0, 1, b1);
        RD_A(1, 1);
        stageA(1, 0, t2 + 3);
        // ---- P7: Q(1,0); post-read b0<-buf0.B0 (next tile); stage buf1.B0<-t2+3
        BARRIER();
        WAIT_LGKM0();
        QUAD(1, 0, b0);
        RD_B(b0, 0, 0);
        stageB(1, 0, t2 + 3);
        // ---- P8: Q(1,1); post-read af<-buf0.A0 (next tile); stage buf1.B1<-t2+3; vmcnt
        BARRIER();
        QUAD(1, 1, b1);
        RD_A(0, 0);
        stageB(1, 1, t2 + 3);
        if (t < NITER - 1) { VMCNT(2); } else { VMCNT(0); }
    }

    // epilogue: region uniform per block (n0 multiple of 256)
    int region = n0 >> 10;
    #pragma unroll
    for (int i = 0; i < 8; ++i) {
        int mh = i >> 2, im = i & 3;
        #pragma unroll
        for (int j = 0; j < 4; ++j) {
            int nh = j >> 1, jn = j & 1;
            f32x4 v = acc[i][j];
            int row0 = m0 + mh * 128 + wm * 64 + im * 16 + l4 * 4;
            int col  = (n0 + nh * 128 + wn * 32 + jn * 16 + l15) & 1023;
            #pragma unroll
            for (int jj = 0; jj < 4; ++jj) {
                int64_t idx = (int64_t)(row0 + jj) * 1024 + col;
                float val = v[jj];
                if (region == 0) {
                    u0_out[idx] = val;
                } else if (region == 1) {
                    fb[idx] = f2bf(1.0f / (1.0f + __expf(-(val + bias[col]))));
                } else {
                    rb[idx] = f2bf(1.0f / (1.0f + __expf(-(val + bias[1024 + col]))));
                }
            }
        }
    }
#undef RD_A
#undef RD_B
#undef QUAD
}

// ---------------- chunked parallel scan ----------------
// c_t = f_t*c_{t-1} + (1-f_t)*u0_t. Chunk transfer: c_out = A*c_in + B.

__global__ void scan_phase1(const unsigned short* __restrict__ fb,
                            const float* __restrict__ u0_arr,
                            float* __restrict__ Aout, float* __restrict__ Bout) {
    int t = blockIdx.x * blockDim.x + threadIdx.x;   // chunk*NBD + idx
    int idx = t & (NBD - 1);
    int chunk = t >> 15;
    int64_t base = (int64_t)chunk * CLEN * NBD + idx;
    float Ap = 1.0f, Bv = 0.0f;
    #pragma unroll 8
    for (int i = 0; i < CLEN; ++i, base += NBD) {
        float f = bf2f(fb[base]);
        float u0 = u0_arr[base];
        Bv = u0 + f * (Bv - u0);
        Ap *= f;
    }
    Aout[t] = Ap; Bout[t] = Bv;
}

__global__ void scan_phase2(const float* __restrict__ c0, const float* __restrict__ Aarr,
                            const float* __restrict__ Barr, float* __restrict__ cin) {
    int idx = blockIdx.x * blockDim.x + threadIdx.x; // 0..NBD-1
    float c = c0[idx];
    #pragma unroll
    for (int ch = 0; ch < NCHUNK; ++ch) {
        cin[ch * NBD + idx] = c;
        c = Aarr[ch * NBD + idx] * c + Barr[ch * NBD + idx];
    }
}

__global__ void scan_phase3(const float* __restrict__ x,
                            const unsigned short* __restrict__ fb,
                            const unsigned short* __restrict__ rb,
                            const float* __restrict__ cin,
                            float* __restrict__ out_h, float* __restrict__ out_c) {
    int t = blockIdx.x * blockDim.x + threadIdx.x;
    int idx = t & (NBD - 1);
    int chunk = t >> 15;
    float c = cin[t];
    int64_t base = (int64_t)chunk * CLEN * NBD + idx;
    #pragma unroll 4
    for (int i = 0; i < CLEN; ++i, base += NBD) {
        float f  = bf2f(fb[base]);
        float u0 = out_c[base];     // u0 written by gemm epilogue
        c = u0 + f * (c - u0);      // f*c + (1-f)*u0
        out_c[base] = c;
        float e = __expf(2.0f * c); // tanh via exp; |c| bounded so no overflow
        float g = (e - 1.0f) / (e + 1.0f);
        float r = bf2f(rb[base]);
        float xv = x[base];
        out_h[base] = xv + r * (g - xv);
    }
}

extern "C" void kernel_launch(void* const* d_in, const int* in_sizes, int n_in,
                              void* d_out, int out_size, void* d_ws, size_t ws_size,
                              hipStream_t stream) {
    const float* x    = (const float*)d_in[0];
    const float* c0   = (const float*)d_in[1];
    const float* wgt  = (const float*)d_in[2];
    const float* bias = (const float*)d_in[3];
    float* out = (float*)d_out;

    unsigned short* xb = (unsigned short*)d_ws;                 // 64 MB (dead after gemm)
    unsigned short* wT = xb + (int64_t)M_DIM * K_DIM;           // +6 MB
    unsigned short* fb = wT + (int64_t)N3_DIM * K_DIM;          // +64 MB, f bf16
    unsigned short* rb = fb + LBD;                              // +64 MB, r bf16

    // A/B/cin overlay the xb region (xb is dead once gemm completes)
    float* Aarr = (float*)d_ws;                                 // 4 MB
    float* Barr = Aarr + NCHUNK * NBD;                          // 4 MB
    float* cin  = Barr + NCHUNK * NBD;                          // 4 MB

    cvt_x_kernel<<<8192, 256, 0, stream>>>(x, xb);
    cvt_w_kernel<<<768, 256, 0, stream>>>(wgt, wT);
    gemm_kernel<<<NMT * NNT, 512, 0, stream>>>(xb, wT, bias, out + LBD, fb, rb);
    scan_phase1<<<(NCHUNK * NBD) / 256, 256, 0, stream>>>(fb, out + LBD, Aarr, Barr);
    scan_phase2<<<NBD / 256, 256, 0, stream>>>(c0, Aarr, Barr, cin);
    scan_phase3<<<(NCHUNK * NBD) / 256, 256, 0, stream>>>(x, fb, rb, cin, out, out + LBD);
}

// Round 7
// 506.034 us; speedup vs baseline: 1.0618x; 1.0012x over previous
//
#include <hip/hip_runtime.h>
#include <hip/hip_bf16.h>
#include <stdint.h>

#define L_DIM 1024
#define B_DIM 32
#define D_DIM 1024
#define M_DIM (L_DIM * B_DIM)        // 32768 GEMM rows
#define N3_DIM (3 * D_DIM)           // 3072 GEMM cols (u0 | f | r regions)
#define K_DIM D_DIM                  // 1024
#define LBD ((int64_t)L_DIM * B_DIM * D_DIM)  // 33554432
#define NBD (B_DIM * D_DIM)          // 32768 chains
#define NCHUNK 32
#define CLEN 32

// GEMM tiling: m97 geometry (proven ~900 TF structure) + swizzle + TLP
#define BM 128
#define BN 128
#define BK 64
#define NMT (M_DIM / BM)   // 256
#define NNT (N3_DIM / BN)  // 24
#define NKT (K_DIM / BK)   // 16

typedef __bf16 bf16_t;
typedef bf16_t bf16x8 __attribute__((ext_vector_type(8)));
typedef float f32x4 __attribute__((ext_vector_type(4)));

// RTNE fp32 -> bf16 bits
__device__ __forceinline__ unsigned short f2bf(float f) {
    union { float f; unsigned u; } v; v.f = f;
    unsigned u = v.u;
    u += 0x7FFFu + ((u >> 16) & 1u);
    return (unsigned short)(u >> 16);
}
__device__ __forceinline__ float bf2f(unsigned short h) {
    union { unsigned u; float f; } v; v.u = ((unsigned)h) << 16;
    return v.f;
}

// ---------------- convert x: fp32 [L,B,D] -> bf16 [M,K] ----------------
__global__ void cvt_x_kernel(const float* __restrict__ x, unsigned short* __restrict__ xb) {
    int64_t i0 = ((int64_t)blockIdx.x * blockDim.x + threadIdx.x) * 4;
    int64_t stride = (int64_t)gridDim.x * blockDim.x * 4;
    for (int64_t i = i0; i < LBD; i += stride) {
        float4 v = *reinterpret_cast<const float4*>(x + i);
        ushort4 o;
        o.x = f2bf(v.x); o.y = f2bf(v.y); o.z = f2bf(v.z); o.w = f2bf(v.w);
        *reinterpret_cast<ushort4*>(xb + i) = o;
    }
}

// ------------- convert weight: [i(1024)][o(1024)][k(3)] fp32 -> wT [n=k*1024+o][i] bf16 -------------
__global__ void cvt_w_kernel(const float* __restrict__ w, unsigned short* __restrict__ wT) {
    __shared__ float tile[64][65];
    int bid = blockIdx.x;               // 768 = 3(k) * 16(o-tiles) * 16(i-tiles)
    int k  = bid >> 8;
    int o0 = ((bid >> 4) & 15) * 64;
    int i0 = (bid & 15) * 64;
    int t = threadIdx.x;
    {
        int o = t & 63, ib = t >> 6;
        #pragma unroll
        for (int it = 0; it < 16; ++it) {
            int i = ib + it * 4;
            tile[o][i] = w[((int64_t)(i0 + i) * 1024 + (o0 + o)) * 3 + k];
        }
    }
    __syncthreads();
    {
        int i = t & 63, ob = t >> 6;
        #pragma unroll
        for (int ot = 0; ot < 16; ++ot) {
            int o = ob + ot * 4;
            wT[(int64_t)(k * 1024 + o0 + o) * 1024 + (i0 + i)] = f2bf(tile[o][i]);
        }
    }
}

// ---------------- GEMM: m97 2-barrier loop, 128x128, 4 waves, swizzled LDS, XCD nt-banding ----------------
__device__ __forceinline__ void gload_lds16(const void* g, void* l) {
    __builtin_amdgcn_global_load_lds(
        (const __attribute__((address_space(1))) unsigned int*)g,
        (__attribute__((address_space(3))) unsigned int*)l,
        16, 0, 0);
}

__global__ __launch_bounds__(256, 2) void gemm_kernel(
    const unsigned short* __restrict__ A,    // [32768][1024] bf16 bits
    const unsigned short* __restrict__ Bt,   // [3072][1024] bf16 bits
    const float* __restrict__ bias,          // [2048]
    float* __restrict__ u0_out,              // d_out + LBD: u0 fp32
    unsigned short* __restrict__ fb,         // ws: f bf16
    unsigned short* __restrict__ rb)         // ws: r bf16
{
    // 32 KiB single-buffered tiles -> 3-4 blocks/CU (TLP hides barrier drains)
    __shared__ __align__(16) unsigned short a_tile[128 * 64];
    __shared__ __align__(16) unsigned short b_tile[128 * 64];

    int bid = blockIdx.x;
    // XCD nt-banding: each XCD owns 3 n-tiles (B working set = 0.75 MB, L2-resident).
    // Within an XCD, consecutive blocks share mt (A-panel read 3x concurrently).
    int xcd = bid & 7, local = bid >> 3;           // 768 blocks per XCD
    int nt = xcd * 3 + (local % 3);
    int mt = local / 3;
    int m0 = mt * BM, n0 = nt * BN;

    int tid = threadIdx.x;
    int w = tid >> 6, lane = tid & 63;
    int wr = (w >> 1) * 64, wc = (w & 1) * 64;     // 2x2 wave grid, 64x64 per wave
    int l15 = lane & 15, l4 = lane >> 4;
    int pcx = l15 & 7;                             // read-side XOR (row&7)

    // staging: source column pre-swizzled, LDS dest linear (verified 0-conflict pattern)
    int sr = lane >> 3;                            // row within 8-row group (= row&7)
    int sc = ((lane & 7) ^ sr) << 3;               // swizzled 16B chunk in bf16 elems
    const unsigned short* Abase = A  + (int64_t)(m0 + sr) * K_DIM + sc;
    const unsigned short* Bbase = Bt + (int64_t)(n0 + sr) * K_DIM + sc;

    f32x4 acc[4][4];
    #pragma unroll
    for (int i = 0; i < 4; ++i)
        #pragma unroll
        for (int j = 0; j < 4; ++j) acc[i][j] = (f32x4){0.f, 0.f, 0.f, 0.f};

    for (int kt = 0; kt < NKT; ++kt) {
        int k0 = kt * BK;
        __syncthreads();                 // readers of previous tile done
        #pragma unroll
        for (int i = 0; i < 4; ++i) {
            int r0 = (i * 4 + w) * 8;
            gload_lds16(Abase + (int64_t)r0 * K_DIM + k0, &a_tile[r0 * 64]);
            gload_lds16(Bbase + (int64_t)r0 * K_DIM + k0, &b_tile[r0 * 64]);
        }
        __syncthreads();                 // compiler drains vmcnt before barrier

        #pragma unroll
        for (int ks = 0; ks < 2; ++ks) {
            int pc = ((ks * 4 + l4) ^ pcx) << 3;
            bf16x8 af[4], bf[4];
            #pragma unroll
            for (int im = 0; im < 4; ++im)
                af[im] = *reinterpret_cast<const bf16x8*>(&a_tile[(wr + im * 16 + l15) * 64 + pc]);
            #pragma unroll
            for (int jn = 0; jn < 4; ++jn)
                bf[jn] = *reinterpret_cast<const bf16x8*>(&b_tile[(wc + jn * 16 + l15) * 64 + pc]);
            #pragma unroll
            for (int im = 0; im < 4; ++im)
                #pragma unroll
                for (int jn = 0; jn < 4; ++jn)
                    acc[im][jn] = __builtin_amdgcn_mfma_f32_16x16x32_bf16(
                        af[im], bf[jn], acc[im][jn], 0, 0, 0);
        }
    }

    // epilogue: region uniform per block (BN=128 divides 1024)
    int region = n0 >> 10;
    #pragma unroll
    for (int im = 0; im < 4; ++im) {
        #pragma unroll
        for (int jn = 0; jn < 4; ++jn) {
            f32x4 v = acc[im][jn];
            int row0 = m0 + wr + im * 16 + l4 * 4;
            int col  = (n0 + wc + jn * 16 + l15) & 1023;
            #pragma unroll
            for (int jj = 0; jj < 4; ++jj) {
                int64_t idx = (int64_t)(row0 + jj) * 1024 + col;
                float val = v[jj];
                if (region == 0) {
                    u0_out[idx] = val;
                } else if (region == 1) {
                    fb[idx] = f2bf(1.0f / (1.0f + __expf(-(val + bias[col]))));
                } else {
                    rb[idx] = f2bf(1.0f / (1.0f + __expf(-(val + bias[1024 + col]))));
                }
            }
        }
    }
}

// ---------------- chunked parallel scan ----------------
// c_t = f_t*c_{t-1} + (1-f_t)*u0_t. Chunk transfer: c_out = A*c_in + B.

__global__ void scan_phase1(const unsigned short* __restrict__ fb,
                            const float* __restrict__ u0_arr,
                            float* __restrict__ Aout, float* __restrict__ Bout) {
    int t = blockIdx.x * blockDim.x + threadIdx.x;   // chunk*NBD + idx
    int idx = t & (NBD - 1);
    int chunk = t >> 15;
    int64_t base = (int64_t)chunk * CLEN * NBD + idx;
    float Ap = 1.0f, Bv = 0.0f;
    #pragma unroll 8
    for (int i = 0; i < CLEN; ++i, base += NBD) {
        float f = bf2f(fb[base]);
        float u0 = u0_arr[base];
        Bv = u0 + f * (Bv - u0);
        Ap *= f;
    }
    Aout[t] = Ap; Bout[t] = Bv;
}

__global__ void scan_phase2(const float* __restrict__ c0, const float* __restrict__ Aarr,
                            const float* __restrict__ Barr, float* __restrict__ cin) {
    int idx = blockIdx.x * blockDim.x + threadIdx.x; // 0..NBD-1
    float c = c0[idx];
    #pragma unroll
    for (int ch = 0; ch < NCHUNK; ++ch) {
        cin[ch * NBD + idx] = c;
        c = Aarr[ch * NBD + idx] * c + Barr[ch * NBD + idx];
    }
}

__global__ void scan_phase3(const float* __restrict__ x,
                            const unsigned short* __restrict__ fb,
                            const unsigned short* __restrict__ rb,
                            const float* __restrict__ cin,
                            float* __restrict__ out_h, float* __restrict__ out_c) {
    int t = blockIdx.x * blockDim.x + threadIdx.x;
    int idx = t & (NBD - 1);
    int chunk = t >> 15;
    float c = cin[t];
    int64_t base = (int64_t)chunk * CLEN * NBD + idx;
    #pragma unroll 4
    for (int i = 0; i < CLEN; ++i, base += NBD) {
        float f  = bf2f(fb[base]);
        float u0 = out_c[base];     // u0 written by gemm epilogue
        c = u0 + f * (c - u0);      // f*c + (1-f)*u0
        out_c[base] = c;
        float e = __expf(2.0f * c); // tanh via exp; |c| bounded so no overflow
        float g = (e - 1.0f) / (e + 1.0f);
        float r = bf2f(rb[base]);
        float xv = x[base];
        out_h[base] = xv + r * (g - xv);
    }
}

extern "C" void kernel_launch(void* const* d_in, const int* in_sizes, int n_in,
                              void* d_out, int out_size, void* d_ws, size_t ws_size,
                              hipStream_t stream) {
    const float* x    = (const float*)d_in[0];
    const float* c0   = (const float*)d_in[1];
    const float* wgt  = (const float*)d_in[2];
    const float* bias = (const float*)d_in[3];
    float* out = (float*)d_out;

    unsigned short* xb = (unsigned short*)d_ws;                 // 64 MB (dead after gemm)
    unsigned short* wT = xb + (int64_t)M_DIM * K_DIM;           // +6 MB
    unsigned short* fb = wT + (int64_t)N3_DIM * K_DIM;          // +64 MB, f bf16
    unsigned short* rb = fb + LBD;                              // +64 MB, r bf16

    // A/B/cin overlay the xb region (xb is dead once gemm completes)
    float* Aarr = (float*)d_ws;                                 // 4 MB
    float* Barr = Aarr + NCHUNK * NBD;                          // 4 MB
    float* cin  = Barr + NCHUNK * NBD;                          // 4 MB

    cvt_x_kernel<<<8192, 256, 0, stream>>>(x, xb);
    cvt_w_kernel<<<768, 256, 0, stream>>>(wgt, wT);
    gemm_kernel<<<NMT * NNT, 256, 0, stream>>>(xb, wT, bias, out + LBD, fb, rb);
    scan_phase1<<<(NCHUNK * NBD) / 256, 256, 0, stream>>>(fb, out + LBD, Aarr, Barr);
    scan_phase2<<<NBD / 256, 256, 0, stream>>>(c0, Aarr, Barr, cin);
    scan_phase3<<<(NCHUNK * NBD) / 256, 256, 0, stream>>>(x, fb, rb, cin, out, out + LBD);
}

// Round 8
// 465.783 us; speedup vs baseline: 1.1536x; 1.0864x over previous
//
#include <hip/hip_runtime.h>
#include <hip/hip_bf16.h>
#include <stdint.h>

#define L_DIM 1024
#define B_DIM 32
#define D_DIM 1024
#define M_DIM (L_DIM * B_DIM)        // 32768 GEMM rows
#define N3_DIM (3 * D_DIM)           // 3072 GEMM cols (u0 | f | r regions)
#define K_DIM D_DIM                  // 1024
#define LBD ((int64_t)L_DIM * B_DIM * D_DIM)  // 33554432
#define NBD (B_DIM * D_DIM)          // 32768 chains
#define NCHUNK 32
#define CLEN 32

// GEMM tiling: m97 geometry + swizzle + TLP (round-7 proven)
#define BM 128
#define BN 128
#define BK 64
#define NMT (M_DIM / BM)   // 256
#define NNT (N3_DIM / BN)  // 24
#define NKT (K_DIM / BK)   // 16

typedef __bf16 bf16_t;
typedef bf16_t bf16x8 __attribute__((ext_vector_type(8)));
typedef float f32x4 __attribute__((ext_vector_type(4)));

// RTNE fp32 -> bf16 bits
__device__ __forceinline__ unsigned short f2bf(float f) {
    union { float f; unsigned u; } v; v.f = f;
    unsigned u = v.u;
    u += 0x7FFFu + ((u >> 16) & 1u);
    return (unsigned short)(u >> 16);
}
__device__ __forceinline__ float bf2f(unsigned short h) {
    union { unsigned u; float f; } v; v.u = ((unsigned)h) << 16;
    return v.f;
}

// ---------------- fused converts: x fp32->bf16 (blocks 0..8191), weight permute (blocks 8192..8959) ----------------
__global__ void cvt_kernel(const float* __restrict__ x, unsigned short* __restrict__ xb,
                           const float* __restrict__ w, unsigned short* __restrict__ wT) {
    __shared__ float tile[64][65];
    int bid = blockIdx.x;
    if (bid < 8192) {
        int64_t i0 = ((int64_t)bid * blockDim.x + threadIdx.x) * 4;
        const int64_t stride = (int64_t)8192 * 256 * 4;
        for (int64_t i = i0; i < LBD; i += stride) {
            float4 v = *reinterpret_cast<const float4*>(x + i);
            ushort4 o;
            o.x = f2bf(v.x); o.y = f2bf(v.y); o.z = f2bf(v.z); o.w = f2bf(v.w);
            *reinterpret_cast<ushort4*>(xb + i) = o;
        }
    } else {
        int wb = bid - 8192;            // 768 = 3(k) * 16(o-tiles) * 16(i-tiles)
        int k  = wb >> 8;
        int o0 = ((wb >> 4) & 15) * 64;
        int i0 = (wb & 15) * 64;
        int t = threadIdx.x;
        {
            int o = t & 63, ib = t >> 6;
            #pragma unroll
            for (int it = 0; it < 16; ++it) {
                int i = ib + it * 4;
                tile[o][i] = w[((int64_t)(i0 + i) * 1024 + (o0 + o)) * 3 + k];
            }
        }
        __syncthreads();
        {
            int i = t & 63, ob = t >> 6;
            #pragma unroll
            for (int ot = 0; ot < 16; ++ot) {
                int o = ob + ot * 4;
                wT[(int64_t)(k * 1024 + o0 + o) * 1024 + (i0 + i)] = f2bf(tile[o][i]);
            }
        }
    }
}

// ---------------- GEMM: m97 2-barrier loop, 128x128, 4 waves, swizzled LDS, XCD nt-banding ----------------
__device__ __forceinline__ void gload_lds16(const void* g, void* l) {
    __builtin_amdgcn_global_load_lds(
        (const __attribute__((address_space(1))) unsigned int*)g,
        (__attribute__((address_space(3))) unsigned int*)l,
        16, 0, 0);
}

__global__ __launch_bounds__(256, 4) void gemm_kernel(
    const unsigned short* __restrict__ A,    // [32768][1024] bf16 bits
    const unsigned short* __restrict__ Bt,   // [3072][1024] bf16 bits
    const float* __restrict__ bias,          // [2048]
    float* __restrict__ u0_out,              // d_out + LBD: u0 fp32 (fallback path)
    unsigned short* __restrict__ fb,         // ws: f bf16
    unsigned short* __restrict__ rb,         // ws: r bf16
    unsigned short* __restrict__ u0b,        // ws: u0 bf16 (fast path) or null
    int useU0b)
{
    // 32 KiB single-buffered tiles -> 4 blocks/CU (TLP hides barrier drains)
    __shared__ __align__(16) unsigned short a_tile[128 * 64];
    __shared__ __align__(16) unsigned short b_tile[128 * 64];

    int bid = blockIdx.x;
    // XCD nt-banding: each XCD owns 3 n-tiles (B working set = 0.75 MB, L2-resident).
    int xcd = bid & 7, local = bid >> 3;           // 768 blocks per XCD
    int nt = xcd * 3 + (local % 3);
    int mt = local / 3;
    int m0 = mt * BM, n0 = nt * BN;

    int tid = threadIdx.x;
    int w = tid >> 6, lane = tid & 63;
    int wr = (w >> 1) * 64, wc = (w & 1) * 64;     // 2x2 wave grid, 64x64 per wave
    int l15 = lane & 15, l4 = lane >> 4;
    int pcx = l15 & 7;                             // read-side XOR (row&7)

    // staging: source column pre-swizzled, LDS dest linear (verified 0-conflict pattern)
    int sr = lane >> 3;                            // row within 8-row group (= row&7)
    int sc = ((lane & 7) ^ sr) << 3;               // swizzled 16B chunk in bf16 elems
    const unsigned short* Abase = A  + (int64_t)(m0 + sr) * K_DIM + sc;
    const unsigned short* Bbase = Bt + (int64_t)(n0 + sr) * K_DIM + sc;

    f32x4 acc[4][4];
    #pragma unroll
    for (int i = 0; i < 4; ++i)
        #pragma unroll
        for (int j = 0; j < 4; ++j) acc[i][j] = (f32x4){0.f, 0.f, 0.f, 0.f};

    for (int kt = 0; kt < NKT; ++kt) {
        int k0 = kt * BK;
        __syncthreads();                 // readers of previous tile done
        #pragma unroll
        for (int i = 0; i < 4; ++i) {
            int r0 = (i * 4 + w) * 8;
            gload_lds16(Abase + (int64_t)r0 * K_DIM + k0, &a_tile[r0 * 64]);
            gload_lds16(Bbase + (int64_t)r0 * K_DIM + k0, &b_tile[r0 * 64]);
        }
        __syncthreads();                 // compiler drains vmcnt before barrier

        #pragma unroll
        for (int ks = 0; ks < 2; ++ks) {
            int pc = ((ks * 4 + l4) ^ pcx) << 3;
            bf16x8 af[4], bf[4];
            #pragma unroll
            for (int im = 0; im < 4; ++im)
                af[im] = *reinterpret_cast<const bf16x8*>(&a_tile[(wr + im * 16 + l15) * 64 + pc]);
            #pragma unroll
            for (int jn = 0; jn < 4; ++jn)
                bf[jn] = *reinterpret_cast<const bf16x8*>(&b_tile[(wc + jn * 16 + l15) * 64 + pc]);
            #pragma unroll
            for (int im = 0; im < 4; ++im)
                #pragma unroll
                for (int jn = 0; jn < 4; ++jn)
                    acc[im][jn] = __builtin_amdgcn_mfma_f32_16x16x32_bf16(
                        af[im], bf[jn], acc[im][jn], 0, 0, 0);
        }
    }

    // epilogue: region uniform per block (BN=128 divides 1024)
    int region = n0 >> 10;
    #pragma unroll
    for (int im = 0; im < 4; ++im) {
        #pragma unroll
        for (int jn = 0; jn < 4; ++jn) {
            f32x4 v = acc[im][jn];
            int row0 = m0 + wr + im * 16 + l4 * 4;
            int col  = (n0 + wc + jn * 16 + l15) & 1023;
            #pragma unroll
            for (int jj = 0; jj < 4; ++jj) {
                int64_t idx = (int64_t)(row0 + jj) * 1024 + col;
                float val = v[jj];
                if (region == 0) {
                    if (useU0b) u0b[idx] = f2bf(val);
                    else        u0_out[idx] = val;
                } else if (region == 1) {
                    fb[idx] = f2bf(1.0f / (1.0f + __expf(-(val + bias[col]))));
                } else {
                    rb[idx] = f2bf(1.0f / (1.0f + __expf(-(val + bias[1024 + col]))));
                }
            }
        }
    }
}

// ---------------- chunked parallel scan ----------------
// c_t = f_t*c_{t-1} + (1-f_t)*u0_t. Chunk transfer: c_out = A*c_in + B.

__global__ void scan_phase1(const unsigned short* __restrict__ fb,
                            const float* __restrict__ u0f,
                            const unsigned short* __restrict__ u0b, int useU0b,
                            float* __restrict__ Aout, float* __restrict__ Bout) {
    int t = blockIdx.x * blockDim.x + threadIdx.x;   // chunk*NBD + idx
    int idx = t & (NBD - 1);
    int chunk = t >> 15;
    int64_t base = (int64_t)chunk * CLEN * NBD + idx;
    float Ap = 1.0f, Bv = 0.0f;
    if (useU0b) {
        #pragma unroll 8
        for (int i = 0; i < CLEN; ++i, base += NBD) {
            float f = bf2f(fb[base]);
            float u0 = bf2f(u0b[base]);
            Bv = u0 + f * (Bv - u0);
            Ap *= f;
        }
    } else {
        #pragma unroll 8
        for (int i = 0; i < CLEN; ++i, base += NBD) {
            float f = bf2f(fb[base]);
            float u0 = u0f[base];
            Bv = u0 + f * (Bv - u0);
            Ap *= f;
        }
    }
    Aout[t] = Ap; Bout[t] = Bv;
}

__global__ void scan_phase2(const float* __restrict__ c0, const float* __restrict__ Aarr,
                            const float* __restrict__ Barr, float* __restrict__ cin) {
    int idx = blockIdx.x * blockDim.x + threadIdx.x; // 0..NBD-1
    float c = c0[idx];
    #pragma unroll
    for (int ch = 0; ch < NCHUNK; ++ch) {
        cin[ch * NBD + idx] = c;
        c = Aarr[ch * NBD + idx] * c + Barr[ch * NBD + idx];
    }
}

__global__ void scan_phase3(const float* __restrict__ x,
                            const unsigned short* __restrict__ fb,
                            const unsigned short* __restrict__ rb,
                            const unsigned short* __restrict__ u0b, int useU0b,
                            const float* __restrict__ cin,
                            float* __restrict__ out_h, float* __restrict__ out_c) {
    int t = blockIdx.x * blockDim.x + threadIdx.x;
    int idx = t & (NBD - 1);
    int chunk = t >> 15;
    float c = cin[t];
    int64_t base = (int64_t)chunk * CLEN * NBD + idx;
    if (useU0b) {
        #pragma unroll 4
        for (int i = 0; i < CLEN; ++i, base += NBD) {
            float f  = bf2f(fb[base]);
            float u0 = bf2f(u0b[base]);
            c = u0 + f * (c - u0);      // f*c + (1-f)*u0
            out_c[base] = c;
            float e = __expf(2.0f * c);
            float g = (e - 1.0f) / (e + 1.0f);
            float r = bf2f(rb[base]);
            float xv = x[base];
            out_h[base] = xv + r * (g - xv);
        }
    } else {
        #pragma unroll 4
        for (int i = 0; i < CLEN; ++i, base += NBD) {
            float f  = bf2f(fb[base]);
            float u0 = out_c[base];     // u0 written by gemm epilogue (in-place)
            c = u0 + f * (c - u0);
            out_c[base] = c;
            float e = __expf(2.0f * c);
            float g = (e - 1.0f) / (e + 1.0f);
            float r = bf2f(rb[base]);
            float xv = x[base];
            out_h[base] = xv + r * (g - xv);
        }
    }
}

extern "C" void kernel_launch(void* const* d_in, const int* in_sizes, int n_in,
                              void* d_out, int out_size, void* d_ws, size_t ws_size,
                              hipStream_t stream) {
    const float* x    = (const float*)d_in[0];
    const float* c0   = (const float*)d_in[1];
    const float* wgt  = (const float*)d_in[2];
    const float* bias = (const float*)d_in[3];
    float* out = (float*)d_out;

    unsigned short* xb = (unsigned short*)d_ws;                 // 64 MiB (dead after gemm)
    unsigned short* wT = xb + (int64_t)M_DIM * K_DIM;           // +6 MiB
    unsigned short* fb = wT + (int64_t)N3_DIM * K_DIM;          // +64 MiB, f bf16
    unsigned short* rb = fb + LBD;                              // +64 MiB, r bf16
    // optional u0 bf16 (needs ws >= 262 MiB)
    size_t need = ((size_t)M_DIM * K_DIM + (size_t)N3_DIM * K_DIM + 3 * (size_t)LBD) * 2;
    int useU0b = (ws_size >= need) ? 1 : 0;
    unsigned short* u0b = useU0b ? (rb + LBD) : nullptr;

    // A/B/cin overlay the xb region (xb is dead once gemm completes)
    float* Aarr = (float*)d_ws;                                 // 4 MiB
    float* Barr = Aarr + NCHUNK * NBD;                          // 4 MiB
    float* cin  = Barr + NCHUNK * NBD;                          // 4 MiB

    cvt_kernel<<<8960, 256, 0, stream>>>(x, xb, wgt, wT);
    gemm_kernel<<<NMT * NNT, 256, 0, stream>>>(xb, wT, bias, out + LBD, fb, rb, u0b, useU0b);
    scan_phase1<<<(NCHUNK * NBD) / 256, 256, 0, stream>>>(fb, out + LBD, u0b, useU0b, Aarr, Barr);
    scan_phase2<<<NBD / 256, 256, 0, stream>>>(c0, Aarr, Barr, cin);
    scan_phase3<<<(NCHUNK * NBD) / 256, 256, 0, stream>>>(x, fb, rb, u0b, useU0b, cin, out, out + LBD);
}